// Round 1
// baseline (247.593 us; speedup 1.0000x reference)
//
#include <hip/hip_runtime.h>
#include <hip/hip_bf16.h>

typedef _Float16 half8v __attribute__((ext_vector_type(8)));
typedef float floatx4 __attribute__((ext_vector_type(4)));

#define NB 32
#define NT 2048
#define ND 1024
#define NM (NB * NT)

__device__ __forceinline__ float fast_tanh(float x) {
    x = fminf(9.0f, fmaxf(-9.0f, x));
    float e = __builtin_amdgcn_exp2f(x * 2.8853900817779268f); // e^(2x)
    return (e - 1.0f) * __builtin_amdgcn_rcpf(e + 1.0f);
}

// ---------------- W [K][N] f32  ->  Wt [N][K] fp16 ----------------
__global__ __launch_bounds__(256)
void wt_kernel(const float* __restrict__ W, _Float16* __restrict__ Wt) {
    __shared__ float tile[32][33];
    int tx = threadIdx.x, ty = threadIdx.y;
    int bx = blockIdx.x, by = blockIdx.y;
    #pragma unroll
    for (int i = 0; i < 4; ++i) {
        int y = by * 32 + ty + i * 8;
        tile[ty + i * 8][tx] = W[y * ND + bx * 32 + tx];
    }
    __syncthreads();
    #pragma unroll
    for (int i = 0; i < 4; ++i) {
        int e = bx * 32 + ty + i * 8;
        Wt[e * ND + by * 32 + tx] = (_Float16)tile[tx][ty + i * 8];
    }
}

// ---------------- fused GEMM + tanh + dot(one) -> logits ----------------
// many [M=65536][K=1024] f32, Wt [N=1024][K=1024] fp16, one [32][1024] f32
// logits[m] += sum_n tanh((many@W)[m][n]) * one[b][n]
__global__ __launch_bounds__(256, 2)
void gemm_logits(const float* __restrict__ many, const _Float16* __restrict__ Wt,
                 const float* __restrict__ one, float* __restrict__ logits) {
    __shared__ _Float16 As[128][72];
    __shared__ _Float16 Bs[128][72];

    // XCD-chunked swizzle: 4096 blocks, 8 XCDs, 512 per chunk.
    // j consecutive (same mb, nb=0..7) -> same XCD, sequential order.
    int bid = blockIdx.x;
    int j = (bid & 7) * 512 + (bid >> 3);
    int mb = j >> 3, nb = j & 7;
    int m0 = mb * 128, n0 = nb * 128;

    int tid = threadIdx.x;
    int lane = tid & 63, w = tid >> 6;
    int wr = w >> 1, wc = w & 1;          // 2x2 waves, each 64x64
    int l15 = lane & 15, l4 = lane >> 4;

    floatx4 acc[4][4] = {};

    for (int kb = 0; kb < 1024; kb += 64) {
        __syncthreads();
        // stage A: 128x64 f32 -> fp16 (reg staged, converted)
        #pragma unroll
        for (int i = 0; i < 8; ++i) {
            int idx = i * 256 + tid;
            int row = idx >> 4, c4 = idx & 15;
            const float4 v = *reinterpret_cast<const float4*>(
                many + ((size_t)(m0 + row) << 10) + kb + c4 * 4);
            union { _Float16 h[4]; uint2 u; } p;
            p.h[0] = (_Float16)v.x; p.h[1] = (_Float16)v.y;
            p.h[2] = (_Float16)v.z; p.h[3] = (_Float16)v.w;
            *reinterpret_cast<uint2*>(&As[row][c4 * 4]) = p.u;
        }
        // stage B (Wt rows, already fp16, K-contiguous)
        #pragma unroll
        for (int i = 0; i < 4; ++i) {
            int idx = i * 256 + tid;
            int row = idx >> 3, c8 = idx & 7;
            uint4 v = *reinterpret_cast<const uint4*>(
                Wt + ((size_t)(n0 + row) << 10) + kb + c8 * 8);
            *reinterpret_cast<uint4*>(&Bs[row][c8 * 8]) = v;
        }
        __syncthreads();
        #pragma unroll
        for (int ks = 0; ks < 64; ks += 32) {
            half8v af[4], bf[4];
            #pragma unroll
            for (int mi = 0; mi < 4; ++mi)
                af[mi] = *reinterpret_cast<const half8v*>(&As[wr * 64 + mi * 16 + l15][ks + l4 * 8]);
            #pragma unroll
            for (int ni = 0; ni < 4; ++ni)
                bf[ni] = *reinterpret_cast<const half8v*>(&Bs[wc * 64 + ni * 16 + l15][ks + l4 * 8]);
            #pragma unroll
            for (int mi = 0; mi < 4; ++mi)
                #pragma unroll
                for (int ni = 0; ni < 4; ++ni)
                    acc[mi][ni] = __builtin_amdgcn_mfma_f32_16x16x32_f16(
                        af[mi], bf[ni], acc[mi][ni], 0, 0, 0);
        }
    }

    // epilogue: tanh * one, reduce over columns, atomicAdd logits
    int bidx = m0 >> 11;                   // batch index (128 | 2048)
    float onev[4];
    #pragma unroll
    for (int ni = 0; ni < 4; ++ni)
        onev[ni] = one[(bidx << 10) + n0 + wc * 64 + ni * 16 + l15];

    #pragma unroll
    for (int mi = 0; mi < 4; ++mi) {
        float part[4] = {0.f, 0.f, 0.f, 0.f};
        #pragma unroll
        for (int ni = 0; ni < 4; ++ni)
            #pragma unroll
            for (int b = 0; b < 4; ++b)
                part[b] += fast_tanh(acc[mi][ni][b]) * onev[ni];
        // butterfly over the 16 lanes (l&15) holding different columns
        #pragma unroll
        for (int off = 1; off < 16; off <<= 1)
            #pragma unroll
            for (int b = 0; b < 4; ++b)
                part[b] += __shfl_xor(part[b], off, 64);
        // lane (mi*4+b) of each 16-group writes that row
        #pragma unroll
        for (int b = 0; b < 4; ++b)
            if (l15 == mi * 4 + b)
                atomicAdd(&logits[m0 + wr * 64 + mi * 16 + l4 * 4 + b], part[b]);
    }
}

// ---------------- softmax over T per batch ----------------
__global__ __launch_bounds__(256)
void softmax_kernel(const float* __restrict__ logits, float* __restrict__ att) {
    int b = blockIdx.x, tid = threadIdx.x;
    const float* lr = logits + (b << 11);
    float lv[8];
    float mx = -1e30f;
    #pragma unroll
    for (int i = 0; i < 8; ++i) { lv[i] = lr[tid + (i << 8)]; mx = fmaxf(mx, lv[i]); }
    #pragma unroll
    for (int off = 1; off < 64; off <<= 1) mx = fmaxf(mx, __shfl_xor(mx, off, 64));
    __shared__ float redm[4];
    __shared__ float reds[4];
    int wv = tid >> 6;
    if ((tid & 63) == 0) redm[wv] = mx;
    __syncthreads();
    mx = fmaxf(fmaxf(redm[0], redm[1]), fmaxf(redm[2], redm[3]));
    float s = 0.f;
    #pragma unroll
    for (int i = 0; i < 8; ++i) { lv[i] = expf(lv[i] - mx); s += lv[i]; }
    #pragma unroll
    for (int off = 1; off < 64; off <<= 1) s += __shfl_xor(s, off, 64);
    if ((tid & 63) == 0) reds[wv] = s;
    __syncthreads();
    s = reds[0] + reds[1] + reds[2] + reds[3];
    float inv = 1.0f / (s + 1e-7f);
    #pragma unroll
    for (int i = 0; i < 8; ++i) att[(b << 11) + tid + (i << 8)] = lv[i] * inv;
}

// ---------------- result[b][d] = sum_t many[b][t][d] * att[b][t] ----------------
__global__ __launch_bounds__(256)
void out_kernel(const float* __restrict__ many, const float* __restrict__ att,
                float* __restrict__ out) {
    int b = blockIdx.x >> 4, tch = blockIdx.x & 15;   // 16 t-chunks of 128
    int tid = threadIdx.x;
    __shared__ float aw[128];
    if (tid < 128) aw[tid] = att[(b << 11) + tch * 128 + tid];
    __syncthreads();
    const float* mp = many + (((size_t)b * NT + tch * 128) << 10) + tid * 4;
    float ax = 0.f, ay = 0.f, az = 0.f, aww = 0.f;
    for (int t = 0; t < 128; ++t) {
        float wgt = aw[t];
        float4 v = *reinterpret_cast<const float4*>(mp + ((size_t)t << 10));
        ax = fmaf(v.x, wgt, ax); ay = fmaf(v.y, wgt, ay);
        az = fmaf(v.z, wgt, az); aww = fmaf(v.w, wgt, aww);
    }
    float* op = out + (b << 10) + tid * 4;
    atomicAdd(op + 0, ax); atomicAdd(op + 1, ay);
    atomicAdd(op + 2, az); atomicAdd(op + 3, aww);
}

extern "C" void kernel_launch(void* const* d_in, const int* in_sizes, int n_in,
                              void* d_out, int out_size, void* d_ws, size_t ws_size,
                              hipStream_t stream) {
    const float* one  = (const float*)d_in[0];   // [32][1024]
    const float* many = (const float*)d_in[1];   // [32][2048][1024]
    const float* W    = (const float*)d_in[2];   // [1024][1024]
    float* out = (float*)d_out;                  // [0,32768) result | [32768,98304) att

    _Float16* Wt  = (_Float16*)d_ws;                              // 2 MB
    float* logits = (float*)((char*)d_ws + (size_t)ND * ND * 2);  // 256 KB
    float* att    = out + NB * ND;

    hipMemsetAsync(out, 0, (size_t)NB * ND * sizeof(float), stream);
    hipMemsetAsync(logits, 0, (size_t)NM * sizeof(float), stream);

    wt_kernel<<<dim3(32, 32), dim3(32, 8), 0, stream>>>(W, Wt);
    gemm_logits<<<4096, 256, 0, stream>>>(many, Wt, one, logits);
    softmax_kernel<<<NB, 256, 0, stream>>>(logits, att);
    out_kernel<<<NB * 16, 256, 0, stream>>>(many, att, out);
}

// Round 3
// 242.927 us; speedup vs baseline: 1.0192x; 1.0192x over previous
//
#include <hip/hip_runtime.h>
#include <hip/hip_bf16.h>

typedef _Float16 half8v __attribute__((ext_vector_type(8)));
typedef __fp16  fp16x2 __attribute__((ext_vector_type(2)));   // cvt_pkrtz return type
typedef float floatx4 __attribute__((ext_vector_type(4)));

#define NB 32
#define NT 2048
#define ND 1024
#define NM (NB * NT)

// global->LDS direct DMA, 16B per lane. Linear LDS dest (wave-uniform base +
// lane*16); swizzle is applied on the GLOBAL source address (rule #21).
#define GL16(g, l)                                                             \
    __builtin_amdgcn_global_load_lds(                                          \
        (const __attribute__((address_space(1))) void*)(g),                    \
        (__attribute__((address_space(3))) void*)(l), 16, 0, 0)

__device__ __forceinline__ float fast_tanh(float x) {
    x = fminf(9.0f, fmaxf(-9.0f, x));
    float e = __builtin_amdgcn_exp2f(x * 2.8853900817779268f); // e^(2x)
    return (e - 1.0f) * __builtin_amdgcn_rcpf(e + 1.0f);
}

// ---------------- W [K][N] f32  ->  Wt [N][K] fp16 ----------------
__global__ __launch_bounds__(256)
void wt_kernel(const float* __restrict__ W, _Float16* __restrict__ Wt) {
    __shared__ float tile[32][33];
    int tx = threadIdx.x, ty = threadIdx.y;
    int bx = blockIdx.x, by = blockIdx.y;
    #pragma unroll
    for (int i = 0; i < 4; ++i) {
        int y = by * 32 + ty + i * 8;
        tile[ty + i * 8][tx] = W[y * ND + bx * 32 + tx];
    }
    __syncthreads();
    #pragma unroll
    for (int i = 0; i < 4; ++i) {
        int e = bx * 32 + ty + i * 8;
        Wt[e * ND + by * 32 + tx] = (_Float16)tile[tx][ty + i * 8];
    }
}

// ---------------- fused GEMM + tanh + dot(one) -> logits ----------------
// many [M=65536][K=1024] f32 (A, kept f32 in LDS, cvt_pkrtz at fragment read)
// Wt   [N=1024][K=1024] fp16 (B)
// logits[m] += sum_n tanh((many@W)[m][n]) * one[b][n]
__global__ __launch_bounds__(256, 2)
void gemm_logits(const float* __restrict__ many, const _Float16* __restrict__ Wt,
                 const float* __restrict__ one, float* __restrict__ logits) {
    __shared__ uint4 AsQ[2048];   // 32 KB: A tile f32 [128][64], src-swizzled
    __shared__ uint4 BsQ[1024];   // 16 KB: B tile f16 [128][64], src-swizzled
    char* AsB = (char*)AsQ;
    char* BsB = (char*)BsQ;

    // XCD-chunked swizzle: 4096 blocks, 8 XCDs, 512 per chunk; each XCD gets
    // whole mb rows (all 8 nb) -> A-panel 8x reuse inside one L2.
    int bid = blockIdx.x;
    int j = (bid & 7) * 512 + (bid >> 3);
    int mb = j >> 3, nb = j & 7;
    int m0 = mb * 128, n0 = nb * 128;

    int tid = threadIdx.x;
    int lane = tid & 63, w = tid >> 6;
    int wr = w >> 1, wc = w & 1;          // 2x2 waves, each 64x64
    int l15 = lane & 15, l4 = lane >> 4;

    // ---- staging address precompute (constant per thread except kb term) ----
    // A: 2048 16B-chunks; thread handles chunk = i*256+tid (i=0..7).
    //    row = i*16 + (tid>>4), cc = tid&15; source chunk col = cc ^ (row&7).
    //    (i*16 == 0 mod 8, so the XOR key (tid>>4)&7 is i-invariant.)
    const char* aS = (const char*)many
        + ((size_t)(m0 + (tid >> 4)) << 12)
        + (size_t)(((tid & 15) ^ ((tid >> 4) & 7)) << 4);
    // B: 1024 chunks; chunk = i*256+tid (i=0..3); row = i*32 + (tid>>3), cc = tid&7.
    const char* bS = (const char*)Wt
        + ((size_t)(n0 + (tid >> 3)) << 11)
        + (size_t)(((tid & 7) ^ ((tid >> 3) & 7)) << 4);
    char* aD = AsB + tid * 16;
    char* bD = BsB + tid * 16;

    floatx4 acc[4][4] = {};

    for (int kb = 0; kb < 1024; kb += 64) {
        // stage (direct-to-LDS DMA; no reg round-trip, no VALU convert)
        #pragma unroll
        for (int i = 0; i < 8; ++i)
            GL16(aS + kb * 4 + i * 65536, aD + i * 4096);   // 16 rows * 4096B
        #pragma unroll
        for (int i = 0; i < 4; ++i)
            GL16(bS + kb * 2 + i * 65536, bD + i * 4096);   // 32 rows * 2048B
        __syncthreads();   // compiler drains vmcnt(0) here -> LDS ready

        #pragma unroll
        for (int ks = 0; ks < 64; ks += 32) {
            half8v af[4], bf[4];
            #pragma unroll
            for (int mi = 0; mi < 4; ++mi) {
                int r = wr * 64 + mi * 16 + l15;
                int s = l15 & 7;                       // == r&7
                const char* base = AsB + r * 256;
                int c0 = (ks >> 2) + l4 * 2;           // 16B chunk index
                float4 x = *(const float4*)(base + (size_t)((c0 ^ s) << 4));
                float4 y = *(const float4*)(base + (size_t)(((c0 + 1) ^ s) << 4));
                union { fp16x2 p[4]; half8v h; } u;
                u.p[0] = __builtin_amdgcn_cvt_pkrtz(x.x, x.y);
                u.p[1] = __builtin_amdgcn_cvt_pkrtz(x.z, x.w);
                u.p[2] = __builtin_amdgcn_cvt_pkrtz(y.x, y.y);
                u.p[3] = __builtin_amdgcn_cvt_pkrtz(y.z, y.w);
                af[mi] = u.h;
            }
            #pragma unroll
            for (int ni = 0; ni < 4; ++ni) {
                int r = wc * 64 + ni * 16 + l15;
                int s = l15 & 7;
                int c = (ks >> 3) + l4;
                bf[ni] = *(const half8v*)(BsB + r * 128 + (size_t)((c ^ s) << 4));
            }
            #pragma unroll
            for (int mi = 0; mi < 4; ++mi)
                #pragma unroll
                for (int ni = 0; ni < 4; ++ni)
                    acc[mi][ni] = __builtin_amdgcn_mfma_f32_16x16x32_f16(
                        af[mi], bf[ni], acc[mi][ni], 0, 0, 0);
        }
        __syncthreads();   // all reads done before next overwrite
    }

    // epilogue: tanh * one, reduce over columns, atomicAdd logits
    int bidx = m0 >> 11;                   // batch index (128-row blocks, 2048/batch)
    float onev[4];
    #pragma unroll
    for (int ni = 0; ni < 4; ++ni)
        onev[ni] = one[(bidx << 10) + n0 + wc * 64 + ni * 16 + l15];

    #pragma unroll
    for (int mi = 0; mi < 4; ++mi) {
        float part[4] = {0.f, 0.f, 0.f, 0.f};
        #pragma unroll
        for (int ni = 0; ni < 4; ++ni)
            #pragma unroll
            for (int b = 0; b < 4; ++b)
                part[b] += fast_tanh(acc[mi][ni][b]) * onev[ni];
        #pragma unroll
        for (int off = 1; off < 16; off <<= 1)
            #pragma unroll
            for (int b = 0; b < 4; ++b)
                part[b] += __shfl_xor(part[b], off, 64);
        #pragma unroll
        for (int b = 0; b < 4; ++b)
            if (l15 == mi * 4 + b)
                atomicAdd(&logits[m0 + wr * 64 + mi * 16 + l4 * 4 + b], part[b]);
    }
}

// ---------------- softmax over T per batch ----------------
__global__ __launch_bounds__(256)
void softmax_kernel(const float* __restrict__ logits, float* __restrict__ att) {
    int b = blockIdx.x, tid = threadIdx.x;
    const float* lr = logits + (b << 11);
    float lv[8];
    float mx = -1e30f;
    #pragma unroll
    for (int i = 0; i < 8; ++i) { lv[i] = lr[tid + (i << 8)]; mx = fmaxf(mx, lv[i]); }
    #pragma unroll
    for (int off = 1; off < 64; off <<= 1) mx = fmaxf(mx, __shfl_xor(mx, off, 64));
    __shared__ float redm[4];
    __shared__ float reds[4];
    int wv = tid >> 6;
    if ((tid & 63) == 0) redm[wv] = mx;
    __syncthreads();
    mx = fmaxf(fmaxf(redm[0], redm[1]), fmaxf(redm[2], redm[3]));
    float s = 0.f;
    #pragma unroll
    for (int i = 0; i < 8; ++i) { lv[i] = expf(lv[i] - mx); s += lv[i]; }
    #pragma unroll
    for (int off = 1; off < 64; off <<= 1) s += __shfl_xor(s, off, 64);
    if ((tid & 63) == 0) reds[wv] = s;
    __syncthreads();
    s = reds[0] + reds[1] + reds[2] + reds[3];
    float inv = 1.0f / (s + 1e-7f);
    #pragma unroll
    for (int i = 0; i < 8; ++i) att[(b << 11) + tid + (i << 8)] = lv[i] * inv;
}

// ---------------- result[b][d] = sum_t many[b][t][d] * att[b][t] ----------------
__global__ __launch_bounds__(256)
void out_kernel(const float* __restrict__ many, const float* __restrict__ att,
                float* __restrict__ out) {
    int b = blockIdx.x >> 4, tch = blockIdx.x & 15;   // 16 t-chunks of 128
    int tid = threadIdx.x;
    __shared__ float aw[128];
    if (tid < 128) aw[tid] = att[(b << 11) + tch * 128 + tid];
    __syncthreads();
    const float* mp = many + (((size_t)b * NT + tch * 128) << 10) + tid * 4;
    float ax = 0.f, ay = 0.f, az = 0.f, aww = 0.f;
    for (int t = 0; t < 128; ++t) {
        float wgt = aw[t];
        float4 v = *reinterpret_cast<const float4*>(mp + ((size_t)t << 10));
        ax = fmaf(v.x, wgt, ax); ay = fmaf(v.y, wgt, ay);
        az = fmaf(v.z, wgt, az); aww = fmaf(v.w, wgt, aww);
    }
    float* op = out + (b << 10) + tid * 4;
    atomicAdd(op + 0, ax); atomicAdd(op + 1, ay);
    atomicAdd(op + 2, az); atomicAdd(op + 3, aww);
}

extern "C" void kernel_launch(void* const* d_in, const int* in_sizes, int n_in,
                              void* d_out, int out_size, void* d_ws, size_t ws_size,
                              hipStream_t stream) {
    const float* one  = (const float*)d_in[0];   // [32][1024]
    const float* many = (const float*)d_in[1];   // [32][2048][1024]
    const float* W    = (const float*)d_in[2];   // [1024][1024]
    float* out = (float*)d_out;                  // [0,32768) result | [32768,98304) att

    _Float16* Wt  = (_Float16*)d_ws;                              // 2 MB
    float* logits = (float*)((char*)d_ws + (size_t)ND * ND * 2);  // 256 KB
    float* att    = out + NB * ND;

    (void)hipMemsetAsync(out, 0, (size_t)NB * ND * sizeof(float), stream);
    (void)hipMemsetAsync(logits, 0, (size_t)NM * sizeof(float), stream);

    wt_kernel<<<dim3(32, 32), dim3(32, 8), 0, stream>>>(W, Wt);
    gemm_logits<<<4096, 256, 0, stream>>>(many, Wt, one, logits);
    softmax_kernel<<<NB, 256, 0, stream>>>(logits, att);
    out_kernel<<<NB * 16, 256, 0, stream>>>(many, att, out);
}